// Round 5
// baseline (372.028 us; speedup 1.0000x reference)
//
#include <hip/hip_runtime.h>
#include <hip/hip_bf16.h>
#include <math.h>

#define B_  512
#define DM  1024
#define DI  2048
#define DS  64
#define DTR 64
#define DT  64
#define G_  8
#define E_  4
#define DC  4

typedef __bf16 bf16x8 __attribute__((ext_vector_type(8)));
typedef float  f32x4  __attribute__((ext_vector_type(4)));
typedef unsigned short ushort_t;

__device__ __forceinline__ float bf2f(__hip_bfloat16 h) { return __bfloat162float(h); }
__device__ __forceinline__ __hip_bfloat16 f2bf(float f) { return __float2bfloat16(f); }
__device__ __forceinline__ float sigmoidf_(float x){ return 1.f/(1.f+expf(-x)); }
__device__ __forceinline__ float siluf_(float x){ return x*sigmoidf_(x); }
__device__ __forceinline__ float softplusf_(float x){ return (x>20.f)? x : log1pf(expf(x)); }

__device__ __forceinline__ unsigned int pack2(float a, float b) {
  unsigned short ua = __builtin_bit_cast(unsigned short, (__bf16)a);
  unsigned short ub = __builtin_bit_cast(unsigned short, (__bf16)b);
  return (unsigned int)ua | ((unsigned int)ub << 16);
}
__device__ __forceinline__ uint4 cvt8(float4 v0, float4 v1) {
  uint4 r;
  r.x = pack2(v0.x, v0.y); r.y = pack2(v0.z, v0.w);
  r.z = pack2(v1.x, v1.y); r.w = pack2(v1.z, v1.w);
  return r;
}

struct P {
  const float *uk, *W_in, *b_in, *tk_c, *tk_p, *rW, *rb, *freq, *phase, *kanW;
  const float *W_inproj, *conv_w, *conv_b, *W_x, *W_dt, *dt_bias, *W_delta, *D_skip, *W_out;
  __hip_bfloat16 *Pu, *Xs, *Sz, *Yb, *Acat;
  float *bc, *Part;
  int *bar;                    // software grid-barrier counters (zeroed pre-launch)
  float *out_hk, *out_w, *out_mask;
};

// Software grid barrier: safe because grid(256) <= guaranteed residency
// capacity (LDS 29.7KB -> >=5 blk/CU; launch_bounds(256,2) -> VGPR<=256 ->
// >=2 blk/CU). Device-scope atomics handle cross-XCD L2 non-coherence (G16).
__device__ __forceinline__ void gsync(int* cnt, int target, int tid)
{
  __syncthreads();
  if (tid == 0) {
    __threadfence();   // release all prior global writes device-wide
    __hip_atomic_fetch_add(cnt, 1, __ATOMIC_RELEASE, __HIP_MEMORY_SCOPE_AGENT);
    while (__hip_atomic_load(cnt, __ATOMIC_ACQUIRE, __HIP_MEMORY_SCOPE_AGENT) < target)
      __builtin_amdgcn_s_sleep(2);
    __threadfence();   // acquire remote writes
  }
  __syncthreads();
}

enum EpiKind { EPI_PU=0, EPI_G2=1, EPI_PART=2, EPI_G4=3, EPI_HK=4 };

// One 32xBN tile of C[m,n] = sum_k A[m,k]*B[n,k] (both K-contiguous).
// 4 waves 2x2, wave tile 16x(BN/2), 16x16x32 bf16 MFMA, BK=64, double-buffered
// LDS (stride 72 ushorts -> only 2-way bank aliasing, free per m136).
// CVTA/CVTB: f32 source converted to bf16 during staging. B2: B=[W_dt|W_delta].
template<int BN, int EK, bool CVTA, bool CVTB, bool B2>
__device__ __forceinline__ void gemm_tile(const void* Ap, const void* Bp,
    int Ka, int Kb, int kBase, int T, int N, int bm, int bn, int zslice,
    ushort_t (&sA)[2][2304], ushort_t (&sB)[2][4608], const P& p, int tid)
{
  constexpr int SA = 72;
  constexpr int NB = BN/32;
  constexpr int WNT = BN/32;
  const int wave = tid >> 6, lane = tid & 63;
  const int wm = wave >> 1, wn = wave & 1;
  const int r = lane & 15, q = lane >> 4;

  float4 fa[2]; uint4 ua;
  float4 fb[NB][2]; uint4 ub[NB];

  auto loadT = [&](int k0) {
    { int idx = tid*8; int row = idx>>6, kk = idx&63;
      if constexpr (CVTA) {
        const float* s = (const float*)Ap + (size_t)(bm+row)*Ka + k0 + kk;
        fa[0] = *reinterpret_cast<const float4*>(s);
        fa[1] = *reinterpret_cast<const float4*>(s+4);
      } else {
        ua = *reinterpret_cast<const uint4*>((const __hip_bfloat16*)Ap + (size_t)(bm+row)*Ka + k0 + kk);
      } }
    #pragma unroll
    for (int c=0;c<NB;++c) {
      int idx = tid*8 + c*2048; int row = idx>>6, kk = idx&63;
      if constexpr (B2) {
        const float* bb = (k0==0) ? (const float*)Bp : p.W_delta;
        const float* s = bb + (size_t)(bn+row)*Kb + kk;
        fb[c][0] = *reinterpret_cast<const float4*>(s);
        fb[c][1] = *reinterpret_cast<const float4*>(s+4);
      } else if constexpr (CVTB) {
        const float* s = (const float*)Bp + (size_t)(bn+row)*Kb + k0 + kk;
        fb[c][0] = *reinterpret_cast<const float4*>(s);
        fb[c][1] = *reinterpret_cast<const float4*>(s+4);
      } else {
        ub[c] = *reinterpret_cast<const uint4*>((const __hip_bfloat16*)Bp + (size_t)(bn+row)*Kb + k0 + kk);
      }
    }
  };
  auto writeT = [&](int buf) {
    { int idx = tid*8; int row = idx>>6, kk = idx&63;
      uint4 v; if constexpr (CVTA) v = cvt8(fa[0], fa[1]); else v = ua;
      *reinterpret_cast<uint4*>(&sA[buf][row*SA + kk]) = v; }
    #pragma unroll
    for (int c=0;c<NB;++c) {
      int idx = tid*8 + c*2048; int row = idx>>6, kk = idx&63;
      uint4 v; if constexpr (CVTB || B2) v = cvt8(fb[c][0], fb[c][1]); else v = ub[c];
      *reinterpret_cast<uint4*>(&sB[buf][row*SA + kk]) = v;
    }
  };

  f32x4 acc[WNT];
  #pragma unroll
  for (int j=0;j<WNT;++j) acc[j] = (f32x4){0.f,0.f,0.f,0.f};

  loadT(kBase);
  writeT(0);
  for (int t=0; t<T; ++t) {
    __syncthreads();
    const int cur = t & 1;
    if (t+1 < T) loadT(kBase + (t+1)*64);   // overlaps MFMA below
    #pragma unroll
    for (int ks=0; ks<2; ++ks) {
      bf16x8 af = *reinterpret_cast<const bf16x8*>(&sA[cur][(wm*16+r)*SA + ks*32 + q*8]);
      bf16x8 bfr[WNT];
      #pragma unroll
      for (int nt=0; nt<WNT; ++nt)
        bfr[nt] = *reinterpret_cast<const bf16x8*>(&sB[cur][(wn*(BN/2)+nt*16+r)*SA + ks*32 + q*8]);
      #pragma unroll
      for (int nt=0; nt<WNT; ++nt)
        acc[nt] = __builtin_amdgcn_mfma_f32_16x16x32_bf16(af, bfr[nt], acc[nt], 0,0,0);
    }
    if (t+1 < T) writeT(cur ^ 1);
  }
  __syncthreads();   // protect LDS before this block's next job

  #pragma unroll
  for (int nt=0; nt<WNT; ++nt) {
    #pragma unroll
    for (int i=0;i<4;++i) {
      int grow = bm + wm*16 + q*4 + i;
      int gcol = bn + wn*(BN/2) + nt*16 + r;
      float v = acc[nt][i];
      if constexpr (EK == EPI_PU) {
        p.Pu[(size_t)grow*DM + gcol] = f2bf(v + p.b_in[gcol]);
      } else if constexpr (EK == EPI_G2) {
        if (gcol < DI) {
          float xc = v * p.conv_w[gcol*DC + (DC-1)] + p.conv_b[gcol];
          p.Xs[(size_t)grow*DI + gcol] = f2bf(siluf_(xc));
        } else {
          p.Sz[(size_t)grow*DI + (gcol - DI)] = f2bf(siluf_(v));
        }
      } else if constexpr (EK == EPI_PART) {
        p.Part[(size_t)zslice*(B_*192) + (size_t)grow*192 + gcol] = v;
      } else if constexpr (EK == EPI_G4) {
        float dt  = softplusf_(v + p.dt_bias[gcol]);
        float xsv = bf2f(p.Xs[(size_t)grow*DI + gcol]);
        float szv = bf2f(p.Sz[(size_t)grow*DI + gcol]);
        float y = (dt * xsv * p.bc[grow] + p.D_skip[gcol] * xsv) * szv;
        p.Yb[(size_t)grow*DI + gcol] = f2bf(y);
      } else { // EPI_HK
        p.out_hk[(size_t)grow*DM + gcol] = v;
      }
    }
  }
}

__device__ __forceinline__ void route(float t, const float* rW, const float* rb,
                                      float* w, float* mask, float* wn)
{
  float l[E_];
  float m = -1e30f;
  for (int e=0;e<E_;++e){ l[e] = t*rW[e] + rb[e]; m = fmaxf(m, l[e]); }
  float s = 0.f;
  for (int e=0;e<E_;++e){ w[e] = expf(l[e]-m); s += w[e]; }
  for (int e=0;e<E_;++e) w[e] /= s;
  int i1 = 0;
  for (int e=1;e<E_;++e) if (w[e] > w[i1]) i1 = e;
  int i2 = -1;
  for (int e=0;e<E_;++e) if (e != i1 && (i2 < 0 || w[e] > w[i2])) i2 = e;
  float ssel = w[i1] + w[i2] + 1e-8f;
  for (int e=0;e<E_;++e){
    float mk = (e==i1 || e==i2) ? 1.f : 0.f;
    mask[e] = mk;
    wn[e] = mk * w[e] / ssel;
  }
}

// routing + sin-embedding + kan delta for batch row b; dphi = 512-float LDS.
__device__ __forceinline__ void mote_inline(const P& p, int b, int tid, float* dphi)
{
  if (tid < 64) {
    float t  = p.tk_c[b];
    float tp = p.tk_p[b];
    float w_c[E_], mask_c[E_], wn_c[E_];
    float w_p[E_], mask_p[E_], wn_p[E_];
    route(t,  p.rW, p.rb, w_c, mask_c, wn_c);
    route(tp, p.rW, p.rb, w_p, mask_p, wn_p);
    if (tid < E_) {
      p.out_w[b*E_ + tid]    = w_c[tid];
      p.out_mask[b*E_ + tid] = mask_c[tid];
    }
    float ec = 0.f, epv = 0.f;
    #pragma unroll
    for (int e=0;e<E_;++e) {
      float f  = p.freq[e*DT + tid];
      float ph = p.phase[e*DT + tid];
      ec  += wn_c[e] * sinf(t*f + ph);
      epv += wn_p[e] * sinf(tp*f + ph);
    }
    const float h = 2.f/(G_-1);
    #pragma unroll
    for (int g=0; g<G_; ++g) {
      float gr = -1.f + g*h;
      float a  = (ec - gr)/h;
      float bb = (epv - gr)/h;
      dphi[tid*G_ + g] = expf(-a*a) - expf(-bb*bb);
    }
  }
  __syncthreads();
  if (tid < 64) {
    float accv = 0.f;
    const float* kwrow = p.kanW + tid*DT*G_;
    for (int j=0;j<DT*G_;++j) accv += dphi[j] * kwrow[j];
    p.Acat[b*128 + 64 + tid] = f2bf(accv);
  }
  __syncthreads();   // protect dphi for next loop iteration
}

__global__ __launch_bounds__(256, 2)
void mega_kernel(P p)
{
  __shared__ ushort_t sA[2][2304];
  __shared__ ushort_t sB[2][4608];
  __shared__ float scr[512];
  const int tid = threadIdx.x;
  const int G = gridDim.x;

  // ---- stage A: mote_kan (1 row/job) + G1 (512 jobs, 32M x 32N, K=1024) ----
  for (int b = blockIdx.x; b < B_; b += G)
    mote_inline(p, b, tid, scr);
  for (int job = blockIdx.x; job < 512; job += G) {
    int my = job >> 5, nx = job & 31;
    gemm_tile<32,EPI_PU,true,true,false>(p.uk, p.W_in, DM, DM, 0, 16, DM,
                                         my*32, nx*32, 0, sA, sB, p, tid);
  }
  gsync(p.bar+0, G, tid);

  // ---- stage B: G2 (1024 jobs, 32M x 64N, K=1024) ----
  for (int job = blockIdx.x; job < 1024; job += G) {
    int my = job >> 6, nx = job & 63;
    gemm_tile<64,EPI_G2,false,true,false>(p.Pu, p.W_inproj, DM, DM, 0, 16, 2*DI,
                                          my*32, nx*64, 0, sA, sB, p, tid);
  }
  gsync(p.bar+1, G, tid);

  // ---- stage C: G3 split-K x4 (384 jobs, 32M x 32N, K-chunk 512) ----
  for (int job = blockIdx.x; job < 384; job += G) {
    int z = job / 96, rem = job % 96;
    int my = rem / 6, nx = rem % 6;
    gemm_tile<32,EPI_PART,false,true,false>(p.Xs, p.W_x, DI, DI, z*512, 8, 192,
                                            my*32, nx*32, z, sA, sB, p, tid);
  }
  gsync(p.bar+2, G, tid);

  // ---- stage C2: reduce partials -> Acat[:,0:64] + bc (1 row/job) ----
  for (int row = blockIdx.x; row < B_; row += G) {
    __syncthreads();            // protect scr across iterations
    const int col = tid;
    float s = 0.f;
    if (col < 192) {
      #pragma unroll
      for (int z=0; z<4; ++z) s += p.Part[(size_t)z*(B_*192) + (size_t)row*192 + col];
      if (col < 64) p.Acat[row*128 + col] = f2bf(s);
      else          scr[col - 64] = s;
    }
    __syncthreads();
    if (col < 64) {
      float pv = scr[col] * scr[col + 64];
      #pragma unroll
      for (int off=32; off; off>>=1) pv += __shfl_down(pv, off);
      if (col == 0) p.bc[row] = pv;
    }
  }
  gsync(p.bar+3, G, tid);

  // ---- stage D: G4 (512 jobs, 32M x 64N, K=128, B=[W_dt|W_delta]) ----
  for (int job = blockIdx.x; job < 512; job += G) {
    int my = job >> 5, nx = job & 31;
    gemm_tile<64,EPI_G4,false,true,true>(p.Acat, p.W_dt, 128, 64, 0, 2, DI,
                                         my*32, nx*64, 0, sA, sB, p, tid);
  }
  gsync(p.bar+4, G, tid);

  // ---- stage E: G5 (512 jobs, 32M x 32N, K=2048) -> f32 hk ----
  for (int job = blockIdx.x; job < 512; job += G) {
    int my = job >> 5, nx = job & 31;
    gemm_tile<32,EPI_HK,false,true,false>(p.Yb, p.W_out, DI, DI, 0, 32, DM,
                                          my*32, nx*32, 0, sA, sB, p, tid);
  }
}

extern "C" void kernel_launch(void* const* d_in, const int* in_sizes, int n_in,
                              void* d_out, int out_size, void* d_ws, size_t ws_size,
                              hipStream_t stream)
{
  char* ws = (char*)d_ws;
  P p;
  p.uk      = (const float*)d_in[0];
  p.tk_c    = (const float*)d_in[1];
  p.tk_p    = (const float*)d_in[2];
  p.W_in    = (const float*)d_in[3];
  p.b_in    = (const float*)d_in[4];
  p.rW      = (const float*)d_in[5];
  p.rb      = (const float*)d_in[6];
  p.freq    = (const float*)d_in[7];
  p.phase   = (const float*)d_in[8];
  p.kanW    = (const float*)d_in[9];
  p.W_inproj= (const float*)d_in[10];
  p.conv_w  = (const float*)d_in[11];
  p.conv_b  = (const float*)d_in[12];
  p.W_x     = (const float*)d_in[13];
  p.W_dt    = (const float*)d_in[14];
  p.dt_bias = (const float*)d_in[15];
  p.W_delta = (const float*)d_in[16];
  /* d_in[17] = A_log — dead in the reference math */
  p.D_skip  = (const float*)d_in[18];
  p.W_out   = (const float*)d_in[19];

  p.Pu   = (__hip_bfloat16*)(ws);                                   // 1 MB
  p.Xs   = (__hip_bfloat16*)(ws + (size_t)(1<<20));                 // 2 MB
  p.Sz   = (__hip_bfloat16*)(ws + (size_t)3*(1<<20));               // 2 MB
  p.Yb   = (__hip_bfloat16*)(ws + (size_t)5*(1<<20));               // 2 MB
  p.Acat = (__hip_bfloat16*)(ws + (size_t)7*(1<<20));               // 128 KB
  p.bc   = (float*)         (ws + (size_t)7*(1<<20) + (128<<10));   // 2 KB
  p.bar  = (int*)           (ws + (size_t)7*(1<<20) + (256<<10));   // 64 B
  p.Part = (float*)         (ws + (size_t)8*(1<<20));               // 1.5 MB

  p.out_hk   = (float*)d_out;
  p.out_w    = p.out_hk + (size_t)B_*DM;
  p.out_mask = p.out_w  + (size_t)B_*E_;

  // zero the software-barrier counters (d_ws is re-poisoned before every call)
  hipMemsetAsync(p.bar, 0, 64, stream);

  mega_kernel<<<dim3(256), dim3(256), 0, stream>>>(p);
}